// Round 11
// baseline (118.572 us; speedup 1.0000x reference)
//
#include <hip/hip_runtime.h>
#include <math.h>

#define N_BINS 229
#define MODEL  128
#define OUTD   88
#define WSZ    30
#define WLEN   61
#define BB     4
#define TT     2048
#define CTANH  2.8853900817779268f   // 2*log2(e)

#define ROWS_HE 16
#define ROWS_F  8                    // rows per fused block (1 wave per row)
#define FHALO   71                   // halo rows: hi = wv + w, wv<8, w<64 -> 0..70
#define EPADU   68                   // u32 stride per E halo row

__device__ __forceinline__ float sigmoidf_(float x) {
    return __builtin_amdgcn_rcpf(1.0f + __expf(-x));
}

// ---- Pass 1: H=(spec@W_h+b)*C ; Ebf=bf16(spec@W_e*C) ; S1=spec@W1 ----
// 384 threads: tid<128 H col, <256 E col, <344 S1 col. 16 rows/block.
__global__ __launch_bounds__(384, 6) void k_he(
        const float* __restrict__ spec,
        const float* __restrict__ W_h,
        const float* __restrict__ W_e,
        const float* __restrict__ W1,
        const float* __restrict__ b_attn,
        float* __restrict__ H,
        unsigned int* __restrict__ Ebf,
        float* __restrict__ S1) {
    const int nb  = blockIdx.x;
    const int tid = threadIdx.x;
    __shared__ float s[ROWS_HE * N_BINS];              // 14656 B
    const float4* __restrict__ src4 =
        (const float4*)(spec + (size_t)nb * (ROWS_HE * N_BINS));
    float4* s4 = (float4*)s;
    for (int i = tid; i < (ROWS_HE * N_BINS) / 4; i += 384) s4[i] = src4[i];
    __syncthreads();

    const float* __restrict__ Wp;
    int st, m = 0;
    float bias = 0.0f;
    if (tid < 128)      { m = tid;       Wp = W_h + m; st = MODEL; bias = b_attn[m]; }
    else if (tid < 256) { m = tid - 128; Wp = W_e + m; st = MODEL; }
    else                { m = tid - 256; Wp = W1 + (m < OUTD ? m : 0); st = OUTD; }

    float acc[ROWS_HE];
#pragma unroll
    for (int r = 0; r < ROWS_HE; ++r) acc[r] = 0.0f;

    float cur[8];
#pragma unroll
    for (int j = 0; j < 8; ++j) cur[j] = Wp[j * st];

    for (int batch = 0; batch < 28; ++batch) {         // 28*8 = 224
        const int fb = batch * 8;
        float nxt[8];
        if (batch < 27) {
#pragma unroll
            for (int j = 0; j < 8; ++j) nxt[j] = Wp[(fb + 8 + j) * st];
        }
#pragma unroll
        for (int j = 0; j < 8; ++j) {
            const float wv = cur[j];
#pragma unroll
            for (int r = 0; r < ROWS_HE; ++r)
                acc[r] = fmaf(s[r * N_BINS + fb + j], wv, acc[r]);
        }
        if (batch < 27) {
#pragma unroll
            for (int j = 0; j < 8; ++j) cur[j] = nxt[j];
        }
    }
    for (int f = 224; f < N_BINS; ++f) {
        const float wv = Wp[f * st];
#pragma unroll
        for (int r = 0; r < ROWS_HE; ++r)
            acc[r] = fmaf(s[r * N_BINS + f], wv, acc[r]);
    }

    const int rg0 = nb * ROWS_HE;
    if (tid < 128) {
#pragma unroll
        for (int r = 0; r < ROWS_HE; ++r)
            H[(size_t)(rg0 + r) * MODEL + m] = (acc[r] + bias) * CTANH;
    } else if (tid < 256) {
#pragma unroll
        for (int r = 0; r < ROWS_HE; ++r) {
            const float val = acc[r] * CTANH;              // pre-scaled E
            const float pv  = __shfl_xor(val, 1, 64);
            if ((m & 1) == 0) {                            // even m packs (m, m+1)
                const unsigned int lo = (__float_as_uint(val) + 0x8000u) >> 16;
                const unsigned int hi = (__float_as_uint(pv) + 0x8000u) & 0xFFFF0000u;
                Ebf[(size_t)(rg0 + r) * 64 + (m >> 1)] = hi | lo;
            }
        }
    } else if (tid < 256 + OUTD) {
#pragma unroll
        for (int r = 0; r < ROWS_HE; ++r)
            S1[(size_t)(rg0 + r) * OUTD + m] = acc[r];     // b1 added later
    }
}

// ---- Pass 2 (fused): scores + softmax + 88-dim pooling + sigmoid ----
// 512 threads = 8 waves = 8 rows (1 wave per row), 1024 blocks -> 32 waves/CU.
// LDS union: bf16-E halo during scores, then S1 halo during pooling.
__global__ __launch_bounds__(512, 8) void k_fused(
        const float* __restrict__ H,
        const unsigned int* __restrict__ Ebf,
        const float* __restrict__ v_w,
        const float* __restrict__ S1,
        const float* __restrict__ b1,
        float* __restrict__ pred,
        float* __restrict__ a_out) {
    const int nb   = blockIdx.x;
    const int tid  = threadIdx.x;
    const int wv   = tid >> 6;              // 0..7 = local row
    const int lane = tid & 63;
    const int r0   = nb * ROWS_F;
    const int b    = r0 >> 11;              // T = 2048
    const int t0   = r0 & (TT - 1);
    const int r    = r0 + wv;
    const int t    = t0 + wv;

    __shared__ __align__(16) unsigned char ubuf[FHALO * OUTD * 4];  // 24992 B
    unsigned int* Ebs = (unsigned int*)ubuf;        // [FHALO][EPADU]
    float*        S1h = (float*)ubuf;               // [FHALO][88]
    __shared__ float4 Hs4[ROWS_F * 32];             //  4096 B
    __shared__ float4 Vs4[32];                      //   512 B
    __shared__ float  scA[ROWS_F][64];              //  2048 B
    __shared__ float  cf[ROWS_F][64];               //  2048 B (total ~33.7 KB)

    // ---- stage bf16 E halo (zero outside [0,TT) == reference zero-pad) ----
    const uint4* __restrict__ Eb16 = (const uint4*)Ebf + (size_t)b * TT * 16;
    for (int i = tid; i < FHALO * 16; i += 512) {
        const int row = i >> 4, c = i & 15;
        const int s   = t0 - WSZ + row;
        uint4 v = make_uint4(0u, 0u, 0u, 0u);
        if (s >= 0 && s < TT) v = Eb16[(size_t)s * 16 + c];
        *(uint4*)&Ebs[row * EPADU + (c << 2)] = v;
    }
    if (tid < ROWS_F * 32)
        Hs4[tid] = ((const float4*)H)[(size_t)r0 * 32 + tid];
    else if (tid < ROWS_F * 32 + 32)
        Vs4[tid - ROWS_F * 32] = ((const float4*)v_w)[tid - ROWS_F * 32];
    __syncthreads();

    // ---- scores: quad lane g owns chunks cq=4q+g; w = w0 + 16*it ----
    const int g  = lane & 3;
    const int w0 = lane >> 2;
    int ro[4];
#pragma unroll
    for (int it = 0; it < 4; ++it)
        ro[it] = (wv + w0 + it * 16) * EPADU;       // hi in [0,70]

    const float4* __restrict__ HsR = &Hs4[wv * 32];

    float pp[4] = {0.f, 0.f, 0.f, 0.f};
    float vs = 0.f;
#pragma unroll
    for (int q = 0; q < 8; ++q) {
        const int    cq = (q << 2) + g;
        const float4 hq = HsR[cq];          // pre-scaled by CTANH
        const float4 vq = Vs4[cq];
        vs += (vq.x + vq.y) + (vq.z + vq.w);
        const float nx = -2.f * vq.x, ny = -2.f * vq.y,
                    nz = -2.f * vq.z, nw = -2.f * vq.w;
#pragma unroll
        for (int it = 0; it < 4; ++it) {
            const uint2 e2 = *(const uint2*)&Ebs[ro[it] + (cq << 1)];
            const float f0 = __uint_as_float(e2.x << 16);
            const float f1 = __uint_as_float(e2.x & 0xFFFF0000u);
            const float f2 = __uint_as_float(e2.y << 16);
            const float f3 = __uint_as_float(e2.y & 0xFFFF0000u);
            float u;
            u = __builtin_amdgcn_rcpf(__builtin_amdgcn_exp2f(f0 + hq.x) + 1.f);
            pp[it] = fmaf(nx, u, pp[it]);
            u = __builtin_amdgcn_rcpf(__builtin_amdgcn_exp2f(f1 + hq.y) + 1.f);
            pp[it] = fmaf(ny, u, pp[it]);
            u = __builtin_amdgcn_rcpf(__builtin_amdgcn_exp2f(f2 + hq.z) + 1.f);
            pp[it] = fmaf(nz, u, pp[it]);
            u = __builtin_amdgcn_rcpf(__builtin_amdgcn_exp2f(f3 + hq.w) + 1.f);
            pp[it] = fmaf(nw, u, pp[it]);
        }
    }

    vs += __shfl_xor(vs, 1, 64);
    vs += __shfl_xor(vs, 2, 64);
#pragma unroll
    for (int it = 0; it < 4; ++it) {
        float p = pp[it];
        p += __shfl_xor(p, 1, 64);
        p += __shfl_xor(p, 2, 64);
        const int w = w0 + it * 16;
        if (g == 0 && w < WLEN) scA[wv][w] = p + vs;
    }

    // ---- wave-local softmax; aEff -> cf (masked; slots 61..63 = 0) ----
    {
        float x = (lane < WLEN) ? scA[wv][lane] : -INFINITY;
        float mx = x;
#pragma unroll
        for (int d = 32; d >= 1; d >>= 1) mx = fmaxf(mx, __shfl_xor(mx, d, 64));
        float e = (lane < WLEN) ? __expf(x - mx) : 0.0f;
        float sm = e;
#pragma unroll
        for (int d = 32; d >= 1; d >>= 1) sm += __shfl_xor(sm, d, 64);
        const float a = e * __builtin_amdgcn_rcpf(sm);
        if (lane < WLEN) a_out[(size_t)r * WLEN + lane] = a;
        const int sl = t + lane - WSZ;
        cf[wv][lane] = (lane < WLEN && sl >= 0 && sl < TT) ? a : 0.0f;
    }

    __syncthreads();                        // all waves done reading Ebs

    // ---- re-stage union with S1 halo (zero outside [0,TT)) ----
    const float4* __restrict__ Sb4 = (const float4*)S1 + (size_t)b * TT * 22;
    for (int i = tid; i < FHALO * 22; i += 512) {
        const int row = i / 22, c = i - row * 22;
        const int s   = t0 - WSZ + row;
        float4 v = make_float4(0.f, 0.f, 0.f, 0.f);
        if (s >= 0 && s < TT) v = Sb4[(size_t)s * 22 + c];
        *(float4*)&S1h[row * OUTD + (c << 2)] = v;
    }
    __syncthreads();

    // ---- pooling: pred[t] = sigmoid(sum_w cf[w] * S1h[wv+w] + b1) ----
    const int o2 = 64 + (lane < 24 ? lane : 23);
    float a1 = 0.f, a2 = 0.f;
#pragma unroll 4
    for (int w = 0; w < 64; ++w) {
        const float at = cf[wv][w];                     // LDS broadcast
        const float* __restrict__ rowp = &S1h[(wv + w) * OUTD];
        a1 = fmaf(at, rowp[lane], a1);
        a2 = fmaf(at, rowp[o2],   a2);
    }
    pred[(size_t)r * OUTD + lane] = sigmoidf_(a1 + b1[lane]);
    if (lane < 24)
        pred[(size_t)r * OUTD + 64 + lane] = sigmoidf_(a2 + b1[64 + lane]);
}

extern "C" void kernel_launch(void* const* d_in, const int* in_sizes, int n_in,
                              void* d_out, int out_size, void* d_ws, size_t ws_size,
                              hipStream_t stream) {
    const float* spec   = (const float*)d_in[0];
    const float* W_h    = (const float*)d_in[1];
    const float* W_e    = (const float*)d_in[2];
    const float* b_attn = (const float*)d_in[3];
    const float* v_w    = (const float*)d_in[4];
    const float* W1     = (const float*)d_in[5];
    const float* b1     = (const float*)d_in[6];

    const int n_rows = BB * TT;                       // 8192
    char* ws = (char*)d_ws;
    float*        H   = (float*)ws;                   // 4 MB (CTANH-scaled)
    unsigned int* Ebf = (unsigned int*)(ws + ((size_t)4 << 20));  // 2 MB bf16
    float*        S1  = (float*)(ws + ((size_t)6 << 20));         // 2.875 MB

    float* pred  = (float*)d_out;                     // 8192*88
    float* a_out = pred + (size_t)n_rows * OUTD;      // 8192*61

    k_he   <<<n_rows / ROWS_HE, 384, 0, stream>>>(spec, W_h, W_e, W1, b_attn,
                                                  H, Ebf, S1);
    k_fused<<<n_rows / ROWS_F,  512, 0, stream>>>(H, Ebf, v_w, S1, b1,
                                                  pred, a_out);
}

// Round 12
// 108.497 us; speedup vs baseline: 1.0929x; 1.0929x over previous
//
#include <hip/hip_runtime.h>
#include <math.h>

#define N_BINS 229
#define MODEL  128
#define OUTD   88
#define WSZ    30
#define WLEN   61
#define BB     4
#define TT     2048
#define CTANH  2.8853900817779268f   // 2*log2(e)

#define ROWS_HE 8
#define SPAD    232                  // padded spec row stride (floats), 16B-aligned
#define ROWS_F  16                   // rows per fused block (2 rows per wave)
#define FHALO   79                   // halo rows: hi = lr + w, lr<16, w<64 -> 0..78
#define EPADU   68                   // u32 stride per E halo row

__device__ __forceinline__ float sigmoidf_(float x) {
    return __builtin_amdgcn_rcpf(1.0f + __expf(-x));
}

// ---- Pass 1: H=(spec@W_h+b)*C ; Ebf=bf16(spec@W_e*C) ; S1=spec@W1 ----
// 384 threads: tid<128 H col, <256 E col, <344 S1 col. 8 rows/block, 1024 blocks.
// Inner loop: ds_read_b128 (4 f per LDS instr) -> 1:4 LDS:FMA issue ratio.
__global__ __launch_bounds__(384, 8) void k_he(
        const float* __restrict__ spec,
        const float* __restrict__ W_h,
        const float* __restrict__ W_e,
        const float* __restrict__ W1,
        const float* __restrict__ b_attn,
        float* __restrict__ H,
        unsigned int* __restrict__ Ebf,
        float* __restrict__ S1) {
    const int nb  = blockIdx.x;
    const int tid = threadIdx.x;
    __shared__ float s[ROWS_HE * SPAD];                // 7424 B, zero-padded tail
    const float* __restrict__ base = spec + (size_t)nb * (ROWS_HE * N_BINS);
#pragma unroll
    for (int r = 0; r < ROWS_HE; ++r) {
        if (tid < SPAD)
            s[r * SPAD + tid] = (tid < N_BINS) ? base[r * N_BINS + tid] : 0.0f;
    }
    __syncthreads();

    const float* __restrict__ Wp;
    int st, m = 0;
    float bias = 0.0f;
    if (tid < 128)      { m = tid;       Wp = W_h + m; st = MODEL; bias = b_attn[m]; }
    else if (tid < 256) { m = tid - 128; Wp = W_e + m; st = MODEL; }
    else                { m = tid - 256; Wp = W1 + (m < OUTD ? m : 0); st = OUTD; }

    float acc[ROWS_HE];
#pragma unroll
    for (int r = 0; r < ROWS_HE; ++r) acc[r] = 0.0f;

    float cur[8];
#pragma unroll
    for (int j = 0; j < 8; ++j) cur[j] = Wp[j * st];

    for (int batch = 0; batch < 29; ++batch) {         // 29*8 = 232 (padded)
        const int fb = batch * 8;
        float nxt[8];
        if (batch < 28) {
#pragma unroll
            for (int j = 0; j < 8; ++j) {
                const int f = fb + 8 + j;
                nxt[j] = (f < N_BINS) ? Wp[f * st] : 0.0f;   // tail W = 0
            }
        }
#pragma unroll
        for (int r = 0; r < ROWS_HE; ++r) {
            const float4 sa = *(const float4*)&s[r * SPAD + fb];
            const float4 sb = *(const float4*)&s[r * SPAD + fb + 4];
            acc[r] = fmaf(sa.x, cur[0], acc[r]);
            acc[r] = fmaf(sa.y, cur[1], acc[r]);
            acc[r] = fmaf(sa.z, cur[2], acc[r]);
            acc[r] = fmaf(sa.w, cur[3], acc[r]);
            acc[r] = fmaf(sb.x, cur[4], acc[r]);
            acc[r] = fmaf(sb.y, cur[5], acc[r]);
            acc[r] = fmaf(sb.z, cur[6], acc[r]);
            acc[r] = fmaf(sb.w, cur[7], acc[r]);
        }
        if (batch < 28) {
#pragma unroll
            for (int j = 0; j < 8; ++j) cur[j] = nxt[j];
        }
    }

    const int rg0 = nb * ROWS_HE;
    if (tid < 128) {
#pragma unroll
        for (int r = 0; r < ROWS_HE; ++r)
            H[(size_t)(rg0 + r) * MODEL + m] = (acc[r] + bias) * CTANH;
    } else if (tid < 256) {
#pragma unroll
        for (int r = 0; r < ROWS_HE; ++r) {
            const float val = acc[r] * CTANH;              // pre-scaled E
            const float pv  = __shfl_xor(val, 1, 64);
            if ((m & 1) == 0) {                            // even m packs (m, m+1)
                const unsigned int lo = (__float_as_uint(val) + 0x8000u) >> 16;
                const unsigned int hi = (__float_as_uint(pv) + 0x8000u) & 0xFFFF0000u;
                Ebf[(size_t)(rg0 + r) * 64 + (m >> 1)] = hi | lo;
            }
        }
    } else if (tid < 256 + OUTD) {
#pragma unroll
        for (int r = 0; r < ROWS_HE; ++r)
            S1[(size_t)(rg0 + r) * OUTD + m] = acc[r];     // b1 added later
    }
}

// ---- Pass 2 (fused): scores + softmax + 88-dim pooling + sigmoid ----
// 512 threads = 8 waves; wave wv handles rows wv and wv+8 (16 rows/block,
// 512 blocks). LDS union: bf16-E halo during scores, then S1 halo for pooling.
__global__ __launch_bounds__(512, 6) void k_fused(
        const float* __restrict__ H,
        const unsigned int* __restrict__ Ebf,
        const float* __restrict__ v_w,
        const float* __restrict__ S1,
        const float* __restrict__ b1,
        float* __restrict__ pred,
        float* __restrict__ a_out) {
    const int nb   = blockIdx.x;
    const int tid  = threadIdx.x;
    const int wv   = tid >> 6;              // 0..7
    const int lane = tid & 63;
    const int r0   = nb * ROWS_F;
    const int b    = r0 >> 11;              // T = 2048
    const int t0   = r0 & (TT - 1);

    __shared__ __align__(16) unsigned char ubuf[FHALO * OUTD * 4];  // 27808 B
    unsigned int* Ebs = (unsigned int*)ubuf;        // [FHALO][EPADU]
    float*        S1h = (float*)ubuf;               // [FHALO][88]
    __shared__ float4 Hs4[ROWS_F * 32];             //  8192 B
    __shared__ float4 Vs4[32];                      //   512 B
    __shared__ float  scA[ROWS_F][64];              //  4096 B
    __shared__ float  cf[ROWS_F][64];               //  4096 B (total ~44.7 KB)

    // ---- stage bf16 E halo (zero outside [0,TT) == reference zero-pad) ----
    const uint4* __restrict__ Eb16 = (const uint4*)Ebf + (size_t)b * TT * 16;
    for (int i = tid; i < FHALO * 16; i += 512) {
        const int row = i >> 4, c = i & 15;
        const int s   = t0 - WSZ + row;
        uint4 v = make_uint4(0u, 0u, 0u, 0u);
        if (s >= 0 && s < TT) v = Eb16[(size_t)s * 16 + c];
        *(uint4*)&Ebs[row * EPADU + (c << 2)] = v;
    }
    Hs4[tid] = ((const float4*)H)[(size_t)r0 * 32 + tid];   // 512 = 16*32 exactly
    if (tid < 32) Vs4[tid] = ((const float4*)v_w)[tid];
    __syncthreads();

    const int g  = lane & 3;
    const int w0 = lane >> 2;

    // ---- Sum(v_w): hoisted once (broadcast LDS reads) ----
    float vs = 0.f;
#pragma unroll
    for (int q = 0; q < 8; ++q) {
        const float4 vq = Vs4[(q << 2) + g];
        vs += (vq.x + vq.y) + (vq.z + vq.w);
    }
    vs += __shfl_xor(vs, 1, 64);
    vs += __shfl_xor(vs, 2, 64);

    // ---- scores for both rows of this wave ----
#pragma unroll
    for (int rr = 0; rr < 2; ++rr) {
        const int lr = wv + rr * 8;         // local row 0..15
        int ro[4];
#pragma unroll
        for (int it = 0; it < 4; ++it)
            ro[it] = (lr + w0 + it * 16) * EPADU;   // hi in [0,78]

        const float4* __restrict__ HsR = &Hs4[lr * 32];

        float pp[4] = {0.f, 0.f, 0.f, 0.f};
#pragma unroll
        for (int q = 0; q < 8; ++q) {
            const int    cq = (q << 2) + g;
            const float4 hq = HsR[cq];      // pre-scaled by CTANH
            const float4 vq = Vs4[cq];
            const float nx = -2.f * vq.x, ny = -2.f * vq.y,
                        nz = -2.f * vq.z, nw = -2.f * vq.w;
#pragma unroll
            for (int it = 0; it < 4; ++it) {
                const uint2 e2 = *(const uint2*)&Ebs[ro[it] + (cq << 1)];
                const float f0 = __uint_as_float(e2.x << 16);
                const float f1 = __uint_as_float(e2.x & 0xFFFF0000u);
                const float f2 = __uint_as_float(e2.y << 16);
                const float f3 = __uint_as_float(e2.y & 0xFFFF0000u);
                float u;
                u = __builtin_amdgcn_rcpf(__builtin_amdgcn_exp2f(f0 + hq.x) + 1.f);
                pp[it] = fmaf(nx, u, pp[it]);
                u = __builtin_amdgcn_rcpf(__builtin_amdgcn_exp2f(f1 + hq.y) + 1.f);
                pp[it] = fmaf(ny, u, pp[it]);
                u = __builtin_amdgcn_rcpf(__builtin_amdgcn_exp2f(f2 + hq.z) + 1.f);
                pp[it] = fmaf(nz, u, pp[it]);
                u = __builtin_amdgcn_rcpf(__builtin_amdgcn_exp2f(f3 + hq.w) + 1.f);
                pp[it] = fmaf(nw, u, pp[it]);
            }
        }
#pragma unroll
        for (int it = 0; it < 4; ++it) {
            float p = pp[it];
            p += __shfl_xor(p, 1, 64);
            p += __shfl_xor(p, 2, 64);
            const int w = w0 + it * 16;
            if (g == 0 && w < WLEN) scA[lr][w] = p + vs;
        }
    }

    // ---- softmax per row (same wave wrote scA[lr] -> no barrier needed) ----
#pragma unroll
    for (int rr = 0; rr < 2; ++rr) {
        const int lr = wv + rr * 8;
        const int r  = r0 + lr;
        const int t  = t0 + lr;
        float x = (lane < WLEN) ? scA[lr][lane] : -INFINITY;
        float mx = x;
#pragma unroll
        for (int d = 32; d >= 1; d >>= 1) mx = fmaxf(mx, __shfl_xor(mx, d, 64));
        float e = (lane < WLEN) ? __expf(x - mx) : 0.0f;
        float sm = e;
#pragma unroll
        for (int d = 32; d >= 1; d >>= 1) sm += __shfl_xor(sm, d, 64);
        const float a = e * __builtin_amdgcn_rcpf(sm);
        if (lane < WLEN) a_out[(size_t)r * WLEN + lane] = a;
        const int sl = t + lane - WSZ;
        cf[lr][lane] = (lane < WLEN && sl >= 0 && sl < TT) ? a : 0.0f;
    }

    __syncthreads();                        // all waves done reading Ebs

    // ---- re-stage union with S1 halo (zero outside [0,TT)) ----
    const float4* __restrict__ Sb4 = (const float4*)S1 + (size_t)b * TT * 22;
    for (int i = tid; i < FHALO * 22; i += 512) {
        const int row = i / 22, c = i - row * 22;
        const int s   = t0 - WSZ + row;
        float4 v = make_float4(0.f, 0.f, 0.f, 0.f);
        if (s >= 0 && s < TT) v = Sb4[(size_t)s * 22 + c];
        *(float4*)&S1h[row * OUTD + (c << 2)] = v;
    }
    __syncthreads();

    // ---- pooling both rows: pred[t] = sigmoid(sum_w cf[w]*S1h[lr+w] + b1) ----
    const int o2 = 64 + (lane < 24 ? lane : 23);
    const float b1a = b1[lane];
    const float b1b = b1[o2];
#pragma unroll
    for (int rr = 0; rr < 2; ++rr) {
        const int lr = wv + rr * 8;
        const int r  = r0 + lr;
        float a1 = 0.f, a2 = 0.f;
#pragma unroll 4
        for (int w = 0; w < 64; ++w) {
            const float at = cf[lr][w];                 // LDS broadcast
            const float* __restrict__ rowp = &S1h[(lr + w) * OUTD];
            a1 = fmaf(at, rowp[lane], a1);
            a2 = fmaf(at, rowp[o2],   a2);
        }
        pred[(size_t)r * OUTD + lane] = sigmoidf_(a1 + b1a);
        if (lane < 24)
            pred[(size_t)r * OUTD + 64 + lane] = sigmoidf_(a2 + b1b);
    }
}

extern "C" void kernel_launch(void* const* d_in, const int* in_sizes, int n_in,
                              void* d_out, int out_size, void* d_ws, size_t ws_size,
                              hipStream_t stream) {
    const float* spec   = (const float*)d_in[0];
    const float* W_h    = (const float*)d_in[1];
    const float* W_e    = (const float*)d_in[2];
    const float* b_attn = (const float*)d_in[3];
    const float* v_w    = (const float*)d_in[4];
    const float* W1     = (const float*)d_in[5];
    const float* b1     = (const float*)d_in[6];

    const int n_rows = BB * TT;                       // 8192
    char* ws = (char*)d_ws;
    float*        H   = (float*)ws;                   // 4 MB (CTANH-scaled)
    unsigned int* Ebf = (unsigned int*)(ws + ((size_t)4 << 20));  // 2 MB bf16
    float*        S1  = (float*)(ws + ((size_t)6 << 20));         // 2.875 MB

    float* pred  = (float*)d_out;                     // 8192*88
    float* a_out = pred + (size_t)n_rows * OUTD;      // 8192*61

    k_he   <<<n_rows / ROWS_HE, 384, 0, stream>>>(spec, W_h, W_e, W1, b_attn,
                                                  H, Ebf, S1);
    k_fused<<<n_rows / ROWS_F,  512, 0, stream>>>(H, Ebf, v_w, S1, b1,
                                                  pred, a_out);
}